// Round 1
// baseline (109.047 us; speedup 1.0000x reference)
//
#include <hip/hip_runtime.h>
#include <hip/hip_bf16.h>

// Segment-sum pooling: features [N, 128] f32, sorted segment_ids [N] i32,
// out [G, 128] f32.  One block per segment; binary-search the row range;
// float4-coalesced streaming reads; register accumulate; LDS tree reduce;
// single store. No atomics.

__global__ __launch_bounds__(256) void SumPooling_54700703482382_kernel(
    const float4* __restrict__ feat,   // N x 32 float4 (= N x 128 f32)
    const int*    __restrict__ seg,    // N, sorted ascending
    float4*       __restrict__ out,    // G x 32 float4
    int N) {
    const int g = blockIdx.x;

    // lower_bound(seg, g) -> start ; lower_bound(seg, g+1) -> end
    int lo = 0, hi = N;
    while (lo < hi) {
        int mid = (lo + hi) >> 1;
        if (seg[mid] < g) lo = mid + 1; else hi = mid;
    }
    const int start = lo;
    hi = N;
    while (lo < hi) {
        int mid = (lo + hi) >> 1;
        if (seg[mid] < g + 1) lo = mid + 1; else hi = mid;
    }
    const int end = lo;

    const int tid   = threadIdx.x;
    const int c     = tid & 31;   // float4 column group (0..31) -> cols 4c..4c+3
    const int rlane = tid >> 5;   // 0..7: which row within a group of 8

    float4 acc = make_float4(0.f, 0.f, 0.f, 0.f);
    #pragma unroll 4
    for (int r = start + rlane; r < end; r += 8) {
        float4 v = feat[(size_t)r * 32 + c];
        acc.x += v.x; acc.y += v.y; acc.z += v.z; acc.w += v.w;
    }

    __shared__ float4 red[256];
    red[tid] = acc;
    __syncthreads();
    if (tid < 128) {
        float4 o = red[tid + 128];
        red[tid].x += o.x; red[tid].y += o.y; red[tid].z += o.z; red[tid].w += o.w;
    }
    __syncthreads();
    if (tid < 64) {
        float4 o = red[tid + 64];
        red[tid].x += o.x; red[tid].y += o.y; red[tid].z += o.z; red[tid].w += o.w;
    }
    __syncthreads();
    if (tid < 32) {
        float4 o = red[tid + 32];
        float4 r0 = red[tid];
        r0.x += o.x; r0.y += o.y; r0.z += o.z; r0.w += o.w;
        out[(size_t)g * 32 + tid] = r0;
    }
}

extern "C" void kernel_launch(void* const* d_in, const int* in_sizes, int n_in,
                              void* d_out, int out_size, void* d_ws, size_t ws_size,
                              hipStream_t stream) {
    const float4* feat = (const float4*)d_in[0];
    const int*    seg  = (const int*)d_in[1];
    float4*       out  = (float4*)d_out;

    const int N = in_sizes[1];          // number of rows (1048576)
    const int D = in_sizes[0] / N;      // 128
    const int G = out_size / D;         // 1024

    SumPooling_54700703482382_kernel<<<G, 256, 0, stream>>>(feat, seg, out, N);
}

// Round 3
// 91.335 us; speedup vs baseline: 1.1939x; 1.1939x over previous
//
#include <hip/hip_runtime.h>
#include <hip/hip_bf16.h>

// Segment-sum pooling: features [N, 128] f32, sorted segment_ids [N] i32,
// out [G, 128] f32.
//
// Two kernels:
//  1) boundary scatter: offs[g] = first row index of segment g (offs[G] = N).
//     One coalesced pass over seg (4 MB) — replaces the per-block binary
//     search (40 dependent loads) that idled the HBM pipe at kernel start.
//  2) main: one block per segment; nontemporal float4 streaming reads
//     (read-once data, skip L2/L3 pollution); register accumulate; LDS tree
//     reduce; one float4 store per lane. No atomics, fully deterministic.

typedef float v4f __attribute__((ext_vector_type(4)));  // clang-native; OK for nontemporal builtins

__global__ __launch_bounds__(256) void seg_boundaries_kernel(
    const int* __restrict__ seg, int* __restrict__ offs, int N, int G) {
    int i = blockIdx.x * blockDim.x + threadIdx.x;
    if (i >= N) return;
    int s = seg[i];
    int prev = (i == 0) ? -1 : seg[i - 1];
    // run start: segment ids in (prev, s] begin at row i (empty segs collapse)
    for (int g = prev + 1; g <= s; ++g) offs[g] = i;
    if (i == N - 1) {
        for (int g = s + 1; g <= G; ++g) offs[g] = N;
    }
}

__global__ __launch_bounds__(256) void SumPooling_54700703482382_kernel(
    const v4f* __restrict__ feat,      // N x 32 v4f (= N x 128 f32)
    const int* __restrict__ offs,      // G+1 segment boundaries
    v4f*       __restrict__ out) {     // G x 32 v4f
    const int g     = blockIdx.x;
    const int start = offs[g];
    const int end   = offs[g + 1];

    const int tid   = threadIdx.x;
    const int c     = tid & 31;   // float4 column group (0..31)
    const int rlane = tid >> 5;   // 0..7: row within a group of 8

    v4f acc = (v4f)(0.f);
    const v4f* p = feat + (size_t)start * 32 + (size_t)rlane * 32 + c;
    int iters = (end - start - rlane + 7) >> 3;   // count for r = start+rlane; r < end; r += 8

    #pragma unroll 8
    for (int it = 0; it < iters; ++it) {
        v4f v = __builtin_nontemporal_load(p);
        acc += v;
        p += 8 * 32;
    }

    __shared__ v4f red[256];
    red[tid] = acc;
    __syncthreads();
    if (tid < 128) red[tid] += red[tid + 128];
    __syncthreads();
    if (tid < 64) red[tid] += red[tid + 64];
    __syncthreads();
    if (tid < 32) {
        v4f r0 = red[tid] + red[tid + 32];
        out[(size_t)g * 32 + tid] = r0;
    }
}

extern "C" void kernel_launch(void* const* d_in, const int* in_sizes, int n_in,
                              void* d_out, int out_size, void* d_ws, size_t ws_size,
                              hipStream_t stream) {
    const v4f* feat = (const v4f*)d_in[0];
    const int* seg  = (const int*)d_in[1];
    v4f*       out  = (v4f*)d_out;

    const int N = in_sizes[1];          // 1048576 rows
    const int D = in_sizes[0] / N;      // 128
    const int G = out_size / D;         // 1024

    int* offs = (int*)d_ws;             // G+1 ints

    seg_boundaries_kernel<<<(N + 255) / 256, 256, 0, stream>>>(seg, offs, N, G);
    SumPooling_54700703482382_kernel<<<G, 256, 0, stream>>>(feat, offs, out);
}

// Round 4
// 88.438 us; speedup vs baseline: 1.2330x; 1.0327x over previous
//
#include <hip/hip_runtime.h>
#include <hip/hip_bf16.h>

// Segment-sum pooling: features [N, 128] f32, sorted segment_ids [N] i32,
// out [G, 128] f32.
//
// Single fused kernel, one block per segment:
//  - wave 0 / wave 1 cooperatively find start/end via 64-ary ballot-narrowed
//    lower_bound (~5 probe rounds; round-1 addresses identical across blocks
//    so they're L2-hot). Replaces the separate boundary kernel + graph edge.
//  - nontemporal float4 streaming reads (read-once data, no L2/L3 pollution),
//    register accumulate, LDS tree reduce, one nt float4 store per lane.
//  - no atomics, deterministic; empty segments write zeros.

typedef float v4f __attribute__((ext_vector_type(4)));

// Wave-cooperative lower_bound: first index a with seg[a] >= x.
// Invariant: answer in [lo, hi], seg[lo-1] < x, seg[hi] >= x (virtual sentinels).
__device__ __forceinline__ int wave_lower_bound(const int* __restrict__ seg,
                                                int N, int x) {
    const int lane = threadIdx.x & 63;
    int lo = 0, hi = N;
    while (hi > lo) {
        int w    = hi - lo;
        int step = (w + 63) >> 6;          // ceil(w/64)
        int q    = lo + lane * step;
        bool pred = (q < hi) && (seg[q] < x);
        unsigned long long m = __ballot(pred);
        int c = __popcll(m);               // monotone: lanes 0..c-1 true
        if (c == 0) { hi = lo; break; }    // seg[lo] >= x -> a = lo
        int nhi = lo + c * step;
        if (nhi > hi) nhi = hi;
        lo = lo + (c - 1) * step + 1;
        hi = nhi;
    }
    return lo;
}

__global__ __launch_bounds__(256) void SumPooling_54700703482382_kernel(
    const v4f* __restrict__ feat,      // N x 32 v4f (= N x 128 f32)
    const int* __restrict__ seg,       // N, sorted ascending
    v4f*       __restrict__ out,       // G x 32 v4f
    int N) {
    const int g    = blockIdx.x;
    const int tid  = threadIdx.x;
    const int wave = tid >> 6;

    __shared__ int sb[2];              // sb[0]=start, sb[1]=end
    if (wave < 2) {
        int r = wave_lower_bound(seg, N, g + wave);
        if ((tid & 63) == 0) sb[wave] = r;
    }
    __syncthreads();
    const int start = sb[0];
    const int end   = sb[1];

    const int c     = tid & 31;   // float4 column group (0..31)
    const int rlane = tid >> 5;   // 0..7: row within a group of 8

    v4f acc = (v4f)(0.f);
    const v4f* p = feat + (size_t)start * 32 + (size_t)rlane * 32 + c;
    int iters = (end - start - rlane + 7) >> 3;   // r = start+rlane; r < end; r += 8

    #pragma unroll 8
    for (int it = 0; it < iters; ++it) {
        v4f v = __builtin_nontemporal_load(p);
        acc += v;
        p += 8 * 32;
    }

    __shared__ v4f red[256];
    red[tid] = acc;
    __syncthreads();
    if (tid < 128) red[tid] += red[tid + 128];
    __syncthreads();
    if (tid < 64) red[tid] += red[tid + 64];
    __syncthreads();
    if (tid < 32) {
        v4f r0 = red[tid] + red[tid + 32];
        __builtin_nontemporal_store(r0, &out[(size_t)g * 32 + tid]);
    }
}

extern "C" void kernel_launch(void* const* d_in, const int* in_sizes, int n_in,
                              void* d_out, int out_size, void* d_ws, size_t ws_size,
                              hipStream_t stream) {
    const v4f* feat = (const v4f*)d_in[0];
    const int* seg  = (const int*)d_in[1];
    v4f*       out  = (v4f*)d_out;

    const int N = in_sizes[1];          // 1048576 rows
    const int D = in_sizes[0] / N;      // 128
    const int G = out_size / D;         // 1024

    SumPooling_54700703482382_kernel<<<G, 256, 0, stream>>>(feat, seg, out, N);
}

// Round 5
// 88.321 us; speedup vs baseline: 1.2347x; 1.0013x over previous
//
#include <hip/hip_runtime.h>
#include <hip/hip_bf16.h>

// Segment-sum pooling: features [N, 128] f32, sorted segment_ids [N] i32,
// out [G, 128] f32.
//
// Single fused kernel, one block per segment, 512 threads (8 waves) per block:
//  - 1024 blocks x 8 waves = 4 blocks/CU -> 32 waves/CU (max occupancy) for
//    maximum outstanding-load latency hiding on the streaming read.
//  - waves 0/1 cooperatively find start/end via 64-ary ballot-narrowed
//    lower_bound (~5 probe rounds, round-1 addresses L2/L3-shared across blocks).
//  - nontemporal float4 streaming reads (read-once data), register accumulate,
//    LDS tree reduce, one nt float4 store per lane. No atomics, deterministic;
//    empty segments write zeros.

typedef float v4f __attribute__((ext_vector_type(4)));

// Wave-cooperative lower_bound: first index a with seg[a] >= x.
__device__ __forceinline__ int wave_lower_bound(const int* __restrict__ seg,
                                                int N, int x) {
    const int lane = threadIdx.x & 63;
    int lo = 0, hi = N;
    while (hi > lo) {
        int w    = hi - lo;
        int step = (w + 63) >> 6;          // ceil(w/64)
        int q    = lo + lane * step;
        bool pred = (q < hi) && (seg[q] < x);
        unsigned long long m = __ballot(pred);
        int c = __popcll(m);               // monotone: lanes 0..c-1 true
        if (c == 0) { hi = lo; break; }    // seg[lo] >= x -> a = lo
        int nhi = lo + c * step;
        if (nhi > hi) nhi = hi;
        lo = lo + (c - 1) * step + 1;
        hi = nhi;
    }
    return lo;
}

__global__ __launch_bounds__(512) void SumPooling_54700703482382_kernel(
    const v4f* __restrict__ feat,      // N x 32 v4f (= N x 128 f32)
    const int* __restrict__ seg,       // N, sorted ascending
    v4f*       __restrict__ out,       // G x 32 v4f
    int N) {
    const int g    = blockIdx.x;
    const int tid  = threadIdx.x;
    const int wave = tid >> 6;

    __shared__ int sb[2];              // sb[0]=start, sb[1]=end
    if (wave < 2) {
        int r = wave_lower_bound(seg, N, g + wave);
        if ((tid & 63) == 0) sb[wave] = r;
    }
    __syncthreads();
    const int start = sb[0];
    const int end   = sb[1];

    const int c     = tid & 31;   // float4 column group (0..31)
    const int rlane = tid >> 5;   // 0..15: row within a group of 16

    v4f acc = (v4f)(0.f);
    const v4f* p = feat + (size_t)start * 32 + (size_t)rlane * 32 + c;
    int iters = (end - start - rlane + 15) >> 4;   // r = start+rlane; r < end; r += 16

    #pragma unroll 8
    for (int it = 0; it < iters; ++it) {
        v4f v = __builtin_nontemporal_load(p);
        acc += v;
        p += 16 * 32;
    }

    __shared__ v4f red[512];
    red[tid] = acc;
    __syncthreads();
    if (tid < 256) red[tid] += red[tid + 256];
    __syncthreads();
    if (tid < 128) red[tid] += red[tid + 128];
    __syncthreads();
    if (tid < 64) red[tid] += red[tid + 64];
    __syncthreads();
    if (tid < 32) {
        v4f r0 = red[tid] + red[tid + 32];
        __builtin_nontemporal_store(r0, &out[(size_t)g * 32 + tid]);
    }
}

extern "C" void kernel_launch(void* const* d_in, const int* in_sizes, int n_in,
                              void* d_out, int out_size, void* d_ws, size_t ws_size,
                              hipStream_t stream) {
    const v4f* feat = (const v4f*)d_in[0];
    const int* seg  = (const int*)d_in[1];
    v4f*       out  = (v4f*)d_out;

    const int N = in_sizes[1];          // 1048576 rows
    const int D = in_sizes[0] / N;      // 128
    const int G = out_size / D;         // 1024

    SumPooling_54700703482382_kernel<<<G, 512, 0, stream>>>(feat, seg, out, N);
}